// Round 1
// baseline (12783.206 us; speedup 1.0000x reference)
//
#include <hip/hip_runtime.h>
#include <hip/hip_bf16.h>
#include <stdint.h>

// RVAE forward: 3 sequential GRU scans over L=512, B=256, H=256.
// Decomposition: 32 groups x 8 WGs. group g owns batch rows [8g, 8g+8);
// WG slice s owns hidden units [32s, 32s+32) (96 of 768 gate rows in LDS, fp32).
// Cross-WG state (h, z-partials, zf_seq) exchanged via agent-scope atomics (LLC),
// one group barrier per step, h parity double-buffered.

struct RvaeParams {
  const float *x, *eps;
  const float *fx_W, *fx_b;
  const float *fz_W1, *fz_b1, *fz_W2, *fz_b2;
  const float *p1_Wih, *p1_Whh, *p1_bih, *p1_bhh;
  const float *p2_Wih, *p2_Whh, *p2_bih, *p2_bhh;
  const float *pn_locW, *pn_locb, *pn_scaleW, *pn_scaleb;
  const float *th_Wih, *th_Whh, *th_bih, *th_bhh;
  const float *tn_locW, *tn_locb;
  float* out;
  unsigned* ctr;       // [32] group barrier counters (64B spaced)
  float* hbuf;         // [2][256][256] parity-double-buffered hidden state
  float* zpart;        // [2][32][8][8][8] posterior partial dots
  float* zf_seq;       // [512][256][32]
  __hip_bfloat16* xh;  // [256 wg][512][8][32] backward-GRU history (own slice)
};

__device__ __forceinline__ float agent_load_f32(const float* p) {
  return __hip_atomic_load(p, __ATOMIC_RELAXED, __HIP_MEMORY_SCOPE_AGENT);
}
__device__ __forceinline__ void agent_store_f32(float* p, float v) {
  __hip_atomic_store(p, v, __ATOMIC_RELAXED, __HIP_MEMORY_SCOPE_AGENT);
}
__device__ __forceinline__ unsigned long long agent_load_u64(const unsigned long long* p) {
  return __hip_atomic_load(p, __ATOMIC_RELAXED, __HIP_MEMORY_SCOPE_AGENT);
}
__device__ __forceinline__ float sigm(float xx) { return 1.0f / (1.0f + __expf(-xx)); }
__device__ __forceinline__ float ftanh(float xx) { return 1.0f - 2.0f / (__expf(2.0f * xx) + 1.0f); }
__device__ __forceinline__ float softplusf(float xx) { return (xx > 15.0f) ? xx : log1pf(__expf(xx)); }

// gh = h @ Whh_slice.T : 3 gate rows per thread, k over 256 (LDS, padded stride 260)
__device__ __forceinline__ void gh_part(const float* Wh, const float* hL, int b, int u,
                                        float& ar, float& az, float& an) {
  float r0 = 0.f, z0 = 0.f, n0 = 0.f;
  const float4* h4 = (const float4*)hL + b * 65;
  const float4* wr = (const float4*)Wh + u * 65;
  const float4* wz = (const float4*)Wh + (32 + u) * 65;
  const float4* wn = (const float4*)Wh + (64 + u) * 65;
#pragma unroll 4
  for (int k = 0; k < 64; ++k) {
    float4 hv = h4[k];
    float4 a = wr[k]; float4 c = wz[k]; float4 d = wn[k];
    r0 = fmaf(a.x, hv.x, r0); r0 = fmaf(a.y, hv.y, r0); r0 = fmaf(a.z, hv.z, r0); r0 = fmaf(a.w, hv.w, r0);
    z0 = fmaf(c.x, hv.x, z0); z0 = fmaf(c.y, hv.y, z0); z0 = fmaf(c.z, hv.z, z0); z0 = fmaf(c.w, hv.w, z0);
    n0 = fmaf(d.x, hv.x, n0); n0 = fmaf(d.y, hv.y, n0); n0 = fmaf(d.z, hv.z, n0); n0 = fmaf(d.w, hv.w, n0);
  }
  ar = r0; az = z0; an = n0;
}

template<int KD4>
__device__ __forceinline__ void gi_part(const float* Wi, int strideF4, const float* inL, int b, int u,
                                        float& gr, float& gz, float& gn) {
  float r0 = 0.f, z0 = 0.f, n0 = 0.f;
  const float4* i4 = (const float4*)inL + b * 17;
  const float4* wr = (const float4*)Wi + u * strideF4;
  const float4* wz = (const float4*)Wi + (32 + u) * strideF4;
  const float4* wn = (const float4*)Wi + (64 + u) * strideF4;
#pragma unroll 4
  for (int k = 0; k < KD4; ++k) {
    float4 hv = i4[k];
    float4 a = wr[k]; float4 c = wz[k]; float4 d = wn[k];
    r0 = fmaf(a.x, hv.x, r0); r0 = fmaf(a.y, hv.y, r0); r0 = fmaf(a.z, hv.z, r0); r0 = fmaf(a.w, hv.w, r0);
    z0 = fmaf(c.x, hv.x, z0); z0 = fmaf(c.y, hv.y, z0); z0 = fmaf(c.z, hv.z, z0); z0 = fmaf(c.w, hv.w, z0);
    n0 = fmaf(d.x, hv.x, n0); n0 = fmaf(d.y, hv.y, n0); n0 = fmaf(d.z, hv.z, n0); n0 = fmaf(d.w, hv.w, n0);
  }
  gr = r0; gz = z0; gn = n0;
}

extern "C" __global__ void __launch_bounds__(256, 1) rvae_main(RvaeParams P) {
  __shared__ __align__(16) float Wh[96 * 260];   // Whh slice, row stride 260 (pad: bank spread)
  __shared__ __align__(16) float SB[7584];       // phase1: Wih64[96][68]; phase2: Wih32[96][36]+pnloc[4][516]+pnscale[4][516]; phase3: Wih32
  __shared__ __align__(16) float hL[8 * 260];    // staged full h for the group's 8 batch rows
  __shared__ __align__(16) float inL[8 * 68];    // xf (64) or zf (32) input features
  __shared__ float bihL[96], bhhL[96];
  __shared__ float fxwL[64], fxbL[64];
  __shared__ float fzW1L[8], fzb1L[2], fzW2L[64], fzb2L[32];
  __shared__ float pnlb[4], pnsb[4];
  __shared__ float wred[4 * 8 * 8];
  __shared__ float zred[64];
  __shared__ float ztL[32];
  __shared__ float hmL[16];
  __shared__ float oredL[4 * 8];
  __shared__ float tnwL[32];
  __shared__ unsigned bcount;

  const int tid = threadIdx.x;
  const int wgid = blockIdx.x;
  const int s = wgid >> 5;   // slice 0..7 (members of a group share bid%32 -> same XCD)
  const int g = wgid & 31;   // group 0..31
  const int b_l = tid & 7;   // batch-in-group
  const int u = tid >> 3;    // unit-in-slice 0..31
  const int j = s * 32 + u;  // global hidden unit
  const int bg = g * 8 + b_l;
  unsigned* gctr = P.ctr + g * 16;

  if (tid < 64) { fxwL[tid] = P.fx_W[tid]; fxbL[tid] = P.fx_b[tid]; fzW2L[tid] = P.fz_W2[tid]; }
  if (tid < 8)  fzW1L[tid] = P.fz_W1[tid];
  if (tid < 2)  fzb1L[tid] = P.fz_b1[tid];
  if (tid < 32) fzb2L[tid] = P.fz_b2[tid];
  if (tid < 4)  { pnlb[tid] = P.pn_locb[tid]; pnsb[tid] = P.pn_scaleb[tid]; }
  if (tid == 0) bcount = 0;

  auto gbar = [&]() {
    __syncthreads();
    if (tid == 0) {
      unsigned target = (++bcount) * 8u;
      __hip_atomic_fetch_add(gctr, 1u, __ATOMIC_RELEASE, __HIP_MEMORY_SCOPE_AGENT);
      int guard = 0;
      while (__hip_atomic_load(gctr, __ATOMIC_ACQUIRE, __HIP_MEMORY_SCOPE_AGENT) < target) {
        __builtin_amdgcn_s_sleep(1);
        if (++guard > (1 << 27)) break;  // safety valve: fail loud, never hang
      }
    }
    __syncthreads();
  };

  auto load_whh = [&](const float* Whh) {
    for (int rr = 0; rr < 96; ++rr) {
      int gate = rr >> 5, uu = rr & 31;
      Wh[rr * 260 + tid] = Whh[(gate * 256 + s * 32 + uu) * 256 + tid];
    }
  };
  auto load_wih32 = [&](const float* Wih) {
    for (int blk = 0; blk < 12; ++blk) {
      int rr = blk * 8 + (tid >> 5); int c = tid & 31;
      int gate = rr >> 5, uu = rr & 31;
      SB[rr * 36 + c] = Wih[(gate * 256 + s * 32 + uu) * 32 + c];
    }
  };
  auto load_bias = [&](const float* bih, const float* bhh) {
    if (tid < 96) {
      int gate = tid >> 5, uu = tid & 31;
      bihL[tid] = bih[gate * 256 + s * 32 + uu];
      bhhL[tid] = bhh[gate * 256 + s * 32 + uu];
    }
  };

  //================= Phase 1: backward GRU (phi1), store xh_r (bf16, own slice) ===========
  load_whh(P.p1_Whh);
  for (int blk = 0; blk < 24; ++blk) {
    int rr = blk * 4 + (tid >> 6); int c = tid & 63;
    int gate = rr >> 5, uu = rr & 31;
    SB[rr * 68 + c] = P.p1_Wih[(gate * 256 + s * 32 + uu) * 64 + c];
  }
  load_bias(P.p1_bih, P.p1_bhh);
  agent_store_f32(P.hbuf + bg * 256 + j, 0.0f);   // h0 = 0 (parity 0)
  {
    // featurize x for first step (input column 511)
#pragma unroll
    for (int i = 0; i < 2; ++i) {
      int idx = tid + i * 256; int bb = idx >> 6, k = idx & 63;
      float xv = P.x[(size_t)(g * 8 + bb) * 512 + 511];
      inL[bb * 68 + k] = ftanh(fmaf(xv, fxwL[k], fxbL[k]));
    }
  }
  gbar();
  for (int t = 0; t < 512; ++t) {
    const float* hin = P.hbuf + (t & 1) * 65536 + g * 2048;
    float* hout = P.hbuf + ((t + 1) & 1) * 65536;
    unsigned long long hv[4];
    const unsigned long long* h64 = (const unsigned long long*)hin;
#pragma unroll
    for (int i = 0; i < 4; ++i) hv[i] = agent_load_u64(h64 + tid + i * 256);
    float gr, gz, gn;
    gi_part<16>(SB, 17, inL, b_l, u, gr, gz, gn);   // overlap with h loads in flight
#pragma unroll
    for (int i = 0; i < 4; ++i) {
      int idx = tid + i * 256; int bb = idx >> 7, kp = (idx & 127) * 2;
      union { unsigned long long q; float f[2]; } cv; cv.q = hv[i];
      hL[bb * 260 + kp] = cv.f[0]; hL[bb * 260 + kp + 1] = cv.f[1];
    }
    __syncthreads();
    float ar, az, an;
    gh_part(Wh, hL, b_l, u, ar, az, an);
    float hold = hL[b_l * 260 + j];
    float r = sigm(gr + bihL[u] + ar + bhhL[u]);
    float z = sigm(gz + bihL[32 + u] + az + bhhL[32 + u]);
    float n = ftanh(fmaf(r, an + bhhL[64 + u], gn + bihL[64 + u]));
    float hnew = fmaf(z, hold - n, n);
    int t_in = 511 - t;
    agent_store_f32(hout + bg * 256 + j, hnew);
    P.xh[((size_t)wgid * 512 + t_in) * 256 + b_l * 32 + u] = __float2bfloat16(hnew);
    if (t < 511) {  // featurize next step's input (column t_in-1); safe: after syncthreads
#pragma unroll
      for (int i = 0; i < 2; ++i) {
        int idx = tid + i * 256; int bb = idx >> 6, k = idx & 63;
        float xv = P.x[(size_t)(g * 8 + bb) * 512 + (t_in - 1)];
        inL[bb * 68 + k] = ftanh(fmaf(xv, fxwL[k], fxbL[k]));
      }
    }
    gbar();
  }

  //================= Phase 2: encoder GRU (phi2) + posterior + feat_z =====================
  __syncthreads();
  load_whh(P.p2_Whh);
  load_wih32(P.p2_Wih);
  for (int idx = tid; idx < 2048; idx += 256) {
    int o = idx >> 9, c = idx & 511;
    SB[3456 + o * 516 + c] = P.pn_locW[idx];
    SB[5520 + o * 516 + c] = P.pn_scaleW[idx];
  }
  load_bias(P.p2_bih, P.p2_bhh);
  agent_store_f32(P.hbuf + bg * 256 + j, 0.0f);
  for (int idx = tid; idx < 8 * 68; idx += 256) inL[idx] = 0.0f;  // zf0 = 0
  gbar();
  for (int t = 0; t < 512; ++t) {
    const float* hin = P.hbuf + (t & 1) * 65536 + g * 2048;
    float* hout = P.hbuf + ((t + 1) & 1) * 65536;
    unsigned long long hv[4];
    const unsigned long long* h64 = (const unsigned long long*)hin;
#pragma unroll
    for (int i = 0; i < 4; ++i) hv[i] = agent_load_u64(h64 + tid + i * 256);
    float xhv = __bfloat162float(P.xh[((size_t)wgid * 512 + t) * 256 + b_l * 32 + u]);
    float gr, gz, gn;
    gi_part<8>(SB, 9, inL, b_l, u, gr, gz, gn);
#pragma unroll
    for (int i = 0; i < 4; ++i) {
      int idx = tid + i * 256; int bb = idx >> 7, kp = (idx & 127) * 2;
      union { unsigned long long q; float f[2]; } cv; cv.q = hv[i];
      hL[bb * 260 + kp] = cv.f[0]; hL[bb * 260 + kp + 1] = cv.f[1];
    }
    __syncthreads();
    float ar, az, an;
    gh_part(Wh, hL, b_l, u, ar, az, an);
    float hold = hL[b_l * 260 + j];
    float r = sigm(gr + bihL[u] + ar + bhhL[u]);
    float z = sigm(gz + bihL[32 + u] + az + bhhL[32 + u]);
    float n = ftanh(fmaf(r, an + bhhL[64 + u], gn + bihL[64 + u]));
    float hnew = fmaf(z, hold - n, n);
    agent_store_f32(hout + bg * 256 + j, hnew);
    // posterior partial dots over this WG's 32-unit slice of cat=[zh, xh]
    float p[8];
#pragma unroll
    for (int o = 0; o < 4; ++o)
      p[o] = fmaf(hnew, SB[3456 + o * 516 + j], xhv * SB[3456 + o * 516 + 256 + j]);
#pragma unroll
    for (int o = 0; o < 4; ++o)
      p[4 + o] = fmaf(hnew, SB[5520 + o * 516 + j], xhv * SB[5520 + o * 516 + 256 + j]);
#pragma unroll
    for (int o = 0; o < 8; ++o) {
      float v = p[o];
      v += __shfl_down(v, 32); v += __shfl_down(v, 16); v += __shfl_down(v, 8);
      p[o] = v;
    }
    {
      int lane = tid & 63, wv = tid >> 6;
      if (lane < 8) {
#pragma unroll
        for (int o = 0; o < 8; ++o) wred[wv * 64 + lane * 8 + o] = p[o];
      }
    }
    __syncthreads();
    float* zp = P.zpart + (t & 1) * 16384 + g * 512;
    if (tid < 64) {
      int bb = tid >> 3, o = tid & 7;
      float sum = wred[bb * 8 + o] + wred[64 + bb * 8 + o] + wred[128 + bb * 8 + o] + wred[192 + bb * 8 + o];
      agent_store_f32(zp + s * 64 + bb * 8 + o, sum);
    }
    gbar();
    if (tid < 64) {
      int bb = tid >> 3, o = tid & 7;
      float sum = 0.f;
#pragma unroll
      for (int sp = 0; sp < 8; ++sp) sum += agent_load_f32(zp + sp * 64 + bb * 8 + o);
      zred[bb * 8 + o] = sum;
    }
    __syncthreads();
    if (tid < 32) {
      int bb = tid >> 2, zi = tid & 3;
      float loc = zred[bb * 8 + zi] + pnlb[zi];
      float sc = softplusf(zred[bb * 8 + 4 + zi] + pnsb[zi]);
      float e = P.eps[((size_t)t * 256 + g * 8 + bb) * 4 + zi];
      ztL[bb * 4 + zi] = fmaf(sc, e, loc);
    }
    __syncthreads();
    if (tid < 16) {
      int bb = tid >> 1, m = tid & 1;
      float a = fzb1L[m];
#pragma unroll
      for (int i = 0; i < 4; ++i) a = fmaf(ztL[bb * 4 + i], fzW1L[m * 4 + i], a);
      hmL[bb * 2 + m] = ftanh(a);
    }
    __syncthreads();
    {
      int bb = tid >> 5, o = tid & 31;
      float zf = ftanh(fmaf(hmL[bb * 2], fzW2L[o * 2], fmaf(hmL[bb * 2 + 1], fzW2L[o * 2 + 1], fzb2L[o])));
      inL[bb * 68 + o] = zf;  // next step's GRU2 input; also == zf_seq[t]
      if (s == 0) agent_store_f32(P.zf_seq + ((size_t)t * 256 + g * 8 + bb) * 32 + o, zf);
    }
    __syncthreads();
  }

  //================= Phase 3: decoder GRU (th) + output projection ========================
  __syncthreads();
  load_whh(P.th_Whh);
  load_wih32(P.th_Wih);
  load_bias(P.th_bih, P.th_bhh);
  if (tid < 32) tnwL[tid] = P.tn_locW[s * 32 + tid];
  agent_store_f32(P.hbuf + bg * 256 + j, 0.0f);
  gbar();
  const float tnb = P.tn_locb[0];
  for (int t = 0; t < 512; ++t) {
    const float* hin = P.hbuf + (t & 1) * 65536 + g * 2048;
    float* hout = P.hbuf + ((t + 1) & 1) * 65536;
    unsigned long long hv[4];
    const unsigned long long* h64 = (const unsigned long long*)hin;
#pragma unroll
    for (int i = 0; i < 4; ++i) hv[i] = agent_load_u64(h64 + tid + i * 256);
    {
      int bb = tid >> 5, o = tid & 31;
      inL[bb * 68 + o] = agent_load_f32(P.zf_seq + ((size_t)t * 256 + g * 8 + bb) * 32 + o);
    }
#pragma unroll
    for (int i = 0; i < 4; ++i) {
      int idx = tid + i * 256; int bb = idx >> 7, kp = (idx & 127) * 2;
      union { unsigned long long q; float f[2]; } cv; cv.q = hv[i];
      hL[bb * 260 + kp] = cv.f[0]; hL[bb * 260 + kp + 1] = cv.f[1];
    }
    __syncthreads();
    float gr, gz, gn;
    gi_part<8>(SB, 9, inL, b_l, u, gr, gz, gn);
    float ar, az, an;
    gh_part(Wh, hL, b_l, u, ar, az, an);
    float hold = hL[b_l * 260 + j];
    float r = sigm(gr + bihL[u] + ar + bhhL[u]);
    float z = sigm(gz + bihL[32 + u] + az + bhhL[32 + u]);
    float n = ftanh(fmaf(r, an + bhhL[64 + u], gn + bihL[64 + u]));
    float hnew = fmaf(z, hold - n, n);
    agent_store_f32(hout + bg * 256 + j, hnew);
    float pv = hnew * tnwL[u];
    pv += __shfl_down(pv, 32); pv += __shfl_down(pv, 16); pv += __shfl_down(pv, 8);
    {
      int lane = tid & 63, wv = tid >> 6;
      if (lane < 8) oredL[wv * 8 + lane] = pv;
    }
    __syncthreads();
    if (tid < 8) {
      float v = oredL[tid] + oredL[8 + tid] + oredL[16 + tid] + oredL[24 + tid];
      if (s == 0) v += tnb;
      atomicAdd(P.out + (size_t)(g * 8 + tid) * 512 + t, v);
    }
    gbar();
  }
}

extern "C" void kernel_launch(void* const* d_in, const int* in_sizes, int n_in,
                              void* d_out, int out_size, void* d_ws, size_t ws_size,
                              hipStream_t stream) {
  (void)in_sizes; (void)n_in; (void)ws_size;
  RvaeParams P;
  P.x        = (const float*)d_in[0];
  P.eps      = (const float*)d_in[1];
  P.fx_W     = (const float*)d_in[2];  P.fx_b     = (const float*)d_in[3];
  P.fz_W1    = (const float*)d_in[4];  P.fz_b1    = (const float*)d_in[5];
  P.fz_W2    = (const float*)d_in[6];  P.fz_b2    = (const float*)d_in[7];
  P.p1_Wih   = (const float*)d_in[8];  P.p1_Whh   = (const float*)d_in[9];
  P.p1_bih   = (const float*)d_in[10]; P.p1_bhh   = (const float*)d_in[11];
  P.p2_Wih   = (const float*)d_in[12]; P.p2_Whh   = (const float*)d_in[13];
  P.p2_bih   = (const float*)d_in[14]; P.p2_bhh   = (const float*)d_in[15];
  P.pn_locW  = (const float*)d_in[16]; P.pn_locb  = (const float*)d_in[17];
  P.pn_scaleW= (const float*)d_in[18]; P.pn_scaleb= (const float*)d_in[19];
  P.th_Wih   = (const float*)d_in[20]; P.th_Whh   = (const float*)d_in[21];
  P.th_bih   = (const float*)d_in[22]; P.th_bhh   = (const float*)d_in[23];
  P.tn_locW  = (const float*)d_in[24]; P.tn_locb  = (const float*)d_in[25];
  P.out = (float*)d_out;
  char* ws = (char*)d_ws;
  P.ctr    = (unsigned*)ws;                                   // 2048 B (zeroed below)
  P.hbuf   = (float*)(ws + 4096);                             // 524288 B
  P.zpart  = (float*)(ws + 4096 + 524288);                    // 131072 B
  P.zf_seq = (float*)(ws + 4096 + 524288 + 131072);           // 16777216 B
  P.xh = (__hip_bfloat16*)(ws + 4096 + 524288 + 131072 + 16777216); // 67108864 B

  hipMemsetAsync(d_out, 0, (size_t)out_size * sizeof(float), stream);
  hipMemsetAsync(d_ws, 0, 4096, stream);
  void* args[] = { (void*)&P };
  hipError_t err = hipLaunchCooperativeKernel((void*)rvae_main, dim3(256), dim3(256), args, 0, stream);
  if (err != hipSuccess) {
    // co-residency also holds for a plain launch (256 WGs, 1/CU via 144KB LDS)
    hipLaunchKernelGGL(rvae_main, dim3(256), dim3(256), 0, stream, P);
  }
}

// Round 5
// 11684.927 us; speedup vs baseline: 1.0940x; 1.0940x over previous
//
#include <hip/hip_runtime.h>
#include <hip/hip_bf16.h>
#include <stdint.h>

// RVAE forward: 3 sequential GRU scans (L=512, B=256, H=256).
// 32 groups x 8 WGs; group g owns batch rows [8g,8g+8); WG slice s owns hidden
// units [32s,32s+32). R2: Whh/Wih weights live in VGPRs (thread=(u,kap),
// kap=16-wide K-chunk), 512 threads (2 waves/SIMD), DPP row_shr reduction.

struct RvaeParams {
  const float *x, *eps;
  const float *fx_W, *fx_b;
  const float *fz_W1, *fz_b1, *fz_W2, *fz_b2;
  const float *p1_Wih, *p1_Whh, *p1_bih, *p1_bhh;
  const float *p2_Wih, *p2_Whh, *p2_bih, *p2_bhh;
  const float *pn_locW, *pn_locb, *pn_scaleW, *pn_scaleb;
  const float *th_Wih, *th_Whh, *th_bih, *th_bhh;
  const float *tn_locW, *tn_locb;
  float* out;
  unsigned* ctr;       // [32*16] group barrier counters
  float* hbuf;         // [2][256][256] parity-double-buffered hidden state
  float* zpart;        // [2][32][8][8][8] posterior partial dots
  float* zf_seq;       // [512][256][32]
  __hip_bfloat16* xh;  // [256 wg][512][8][32] backward-GRU history (own slice)
};

__device__ __forceinline__ float agent_load_f32(const float* p) {
  return __hip_atomic_load(p, __ATOMIC_RELAXED, __HIP_MEMORY_SCOPE_AGENT);
}
__device__ __forceinline__ void agent_store_f32(float* p, float v) {
  __hip_atomic_store(p, v, __ATOMIC_RELAXED, __HIP_MEMORY_SCOPE_AGENT);
}
__device__ __forceinline__ unsigned long long agent_load_u64(const unsigned long long* p) {
  return __hip_atomic_load(p, __ATOMIC_RELAXED, __HIP_MEMORY_SCOPE_AGENT);
}
__device__ __forceinline__ float sigm(float v) { return 1.0f / (1.0f + __expf(-v)); }
__device__ __forceinline__ float ftanh(float v) { return 1.0f - 2.0f / (__expf(2.0f * v) + 1.0f); }
__device__ __forceinline__ float softplusf(float v) { return (v > 15.0f) ? v : log1pf(__expf(v)); }

// VALU-pipe 16-lane row reduction: lane (row*16+15) ends with the row sum.
template<int CTRL>
__device__ __forceinline__ float dpp_add(float v) {
  int x = __builtin_amdgcn_update_dpp(0, __float_as_int(v), CTRL, 0xf, 0xf, true);
  return v + __int_as_float(x);
}
__device__ __forceinline__ float row_reduce16(float v) {
  v = dpp_add<0x111>(v);  // row_shr:1
  v = dpp_add<0x112>(v);  // row_shr:2
  v = dpp_add<0x114>(v);  // row_shr:4
  v = dpp_add<0x118>(v);  // row_shr:8
  return v;
}

extern "C" __global__ void __launch_bounds__(512, 2) rvae_main(RvaeParams P) {
  // hL swizzle: h[b][k] at b*320 + (k>>4)*20 + (k&15)  (chunk stride 20 floats
  // = 80B -> 16 kap-chunks spread over all 32 banks, <=2-way aliasing).
  __shared__ __align__(16) float hL[8 * 320];
  __shared__ __align__(16) float inL[8 * 68];     // phase1 stride 68; phase2/3 stride 36
  __shared__ __align__(16) float gsum[8 * 132];   // [b*132 + {0:r,32:z,64:gi_n,96:gh_n} + u]
  __shared__ __align__(16) float SB[2 * 4 * 516]; // posterior weights (phase 2)
  __shared__ float bihL[96], bhhL[96];
  __shared__ float fxwL[64], fxbL[64];
  __shared__ float fzW1L[8], fzb1L[2], fzW2L[64], fzb2L[32];
  __shared__ float pnlb[4], pnsb[4];
  __shared__ float wred[256];
  __shared__ float zred[64];
  __shared__ float ztL[32];
  __shared__ float hmL[16];
  __shared__ float oredL[32];
  __shared__ float tnwL[32];
  __shared__ unsigned bcount;
  __shared__ float lds_pad[11776];  // push LDS > 80KB: guarantees 1 WG/CU

  const int tid = threadIdx.x;
  const int wgid = blockIdx.x;
  const int s = wgid >> 5;          // slice 0..7 (bid%32 const per group -> same XCD)
  const int g = wgid & 31;          // group 0..31
  const int kap = tid & 15;         // K-chunk 0..15
  const int uu = tid >> 4;          // unit-in-slice 0..31
  const int b_l = tid & 7;          // pointwise batch (tid<256)
  const int up = (tid >> 3) & 31;   // pointwise unit (tid<256)
  const int j = s * 32 + up;
  const int bg = g * 8 + b_l;
  unsigned* gctr = P.ctr + g * 16;

  if (tid < 64) { fxwL[tid] = P.fx_W[tid]; fxbL[tid] = P.fx_b[tid]; fzW2L[tid] = P.fz_W2[tid]; }
  if (tid < 8)  fzW1L[tid] = P.fz_W1[tid];
  if (tid < 2)  fzb1L[tid] = P.fz_b1[tid];
  if (tid < 32) { fzb2L[tid] = P.fz_b2[tid]; tnwL[tid] = P.tn_locW[s * 32 + tid]; }
  if (tid < 4)  { pnlb[tid] = P.pn_locb[tid]; pnsb[tid] = P.pn_scaleb[tid]; }
  if (tid == 0) bcount = 0;
  lds_pad[tid] = (float)tid;
  asm volatile("" : : "v"(lds_pad[tid]) : "memory");  // keep pad allocated

  float whr[16], whz[16], whn[16];  // Whh rows (3 gates) for (uu, kap*16..+16)
  float wir[4], wiz[4], win[4];     // Wih chunk (phase1: 4; phase2/3: 2 used)
  float pr[8], pz[8], pni[8], pnh[8];
  unsigned long long q0, q1;

  auto gbar = [&]() {
    __syncthreads();
    if (tid == 0) {
      unsigned target = (++bcount) * 8u;
      __hip_atomic_fetch_add(gctr, 1u, __ATOMIC_RELEASE, __HIP_MEMORY_SCOPE_AGENT);
      int guard = 0;
      while (__hip_atomic_load(gctr, __ATOMIC_ACQUIRE, __HIP_MEMORY_SCOPE_AGENT) < target) {
        __builtin_amdgcn_s_sleep(1);
        if (++guard > (1 << 27)) break;  // fail loud, never hang
      }
    }
    __syncthreads();
  };

  auto load_whh_regs = [&](const float* Whh) {
    const float* base = Whh + (size_t)(s * 32 + uu) * 256 + kap * 16;
#pragma unroll
    for (int c = 0; c < 4; ++c) {
      float4 vr = *(const float4*)(base + c * 4);
      float4 vz = *(const float4*)(base + 65536 + c * 4);
      float4 vn = *(const float4*)(base + 131072 + c * 4);
      whr[4*c+0]=vr.x; whr[4*c+1]=vr.y; whr[4*c+2]=vr.z; whr[4*c+3]=vr.w;
      whz[4*c+0]=vz.x; whz[4*c+1]=vz.y; whz[4*c+2]=vz.z; whz[4*c+3]=vz.w;
      whn[4*c+0]=vn.x; whn[4*c+1]=vn.y; whn[4*c+2]=vn.z; whn[4*c+3]=vn.w;
    }
  };
  auto load_wih64_regs = [&](const float* Wih) {
    const float* base = Wih + (size_t)(s * 32 + uu) * 64 + kap * 4;
    float4 vr = *(const float4*)(base);
    float4 vz = *(const float4*)(base + 16384);
    float4 vn = *(const float4*)(base + 32768);
    wir[0]=vr.x; wir[1]=vr.y; wir[2]=vr.z; wir[3]=vr.w;
    wiz[0]=vz.x; wiz[1]=vz.y; wiz[2]=vz.z; wiz[3]=vz.w;
    win[0]=vn.x; win[1]=vn.y; win[2]=vn.z; win[3]=vn.w;
  };
  auto load_wih32_regs = [&](const float* Wih) {
    const float* base = Wih + (size_t)(s * 32 + uu) * 32 + kap * 2;
    float2 vr = *(const float2*)(base);
    float2 vz = *(const float2*)(base + 8192);
    float2 vn = *(const float2*)(base + 16384);
    wir[0]=vr.x; wir[1]=vr.y; wiz[0]=vz.x; wiz[1]=vz.y; win[0]=vn.x; win[1]=vn.y;
  };
  auto load_bias = [&](const float* bih, const float* bhh) {
    if (tid < 96) {
      int gate = tid >> 5, u2 = tid & 31;
      bihL[tid] = bih[gate * 256 + s * 32 + u2];
      bhhL[tid] = bhh[gate * 256 + s * 32 + u2];
    }
  };
  auto load_h_issue = [&](int t) {  // issue LLC loads early
    const unsigned long long* h64 =
        (const unsigned long long*)(P.hbuf + (t & 1) * 65536 + g * 2048) + tid * 2;
    q0 = agent_load_u64(h64);
    q1 = agent_load_u64(h64 + 1);
  };
  auto stage_h = [&]() {  // swizzled write into hL
    int bb = tid >> 6, k4 = tid & 63;
    union { unsigned long long q[2]; float f[4]; } cv; cv.q[0] = q0; cv.q[1] = q1;
    float* dst = hL + bb * 320 + (k4 >> 2) * 20 + (k4 & 3) * 4;
    *(float4*)dst = make_float4(cv.f[0], cv.f[1], cv.f[2], cv.f[3]);
  };
  auto gh_accum = [&]() {
#pragma unroll
    for (int b = 0; b < 8; ++b) {
      const float* hp = hL + b * 320 + kap * 20;
      float4 hcv[4];
      hcv[0] = *(const float4*)(hp);     hcv[1] = *(const float4*)(hp + 4);
      hcv[2] = *(const float4*)(hp + 8); hcv[3] = *(const float4*)(hp + 12);
      float r = pr[b], z = pz[b], n = pnh[b];
#pragma unroll
      for (int c = 0; c < 4; ++c) {
        r = fmaf(whr[4*c+0], hcv[c].x, r); r = fmaf(whr[4*c+1], hcv[c].y, r);
        r = fmaf(whr[4*c+2], hcv[c].z, r); r = fmaf(whr[4*c+3], hcv[c].w, r);
        z = fmaf(whz[4*c+0], hcv[c].x, z); z = fmaf(whz[4*c+1], hcv[c].y, z);
        z = fmaf(whz[4*c+2], hcv[c].z, z); z = fmaf(whz[4*c+3], hcv[c].w, z);
        n = fmaf(whn[4*c+0], hcv[c].x, n); n = fmaf(whn[4*c+1], hcv[c].y, n);
        n = fmaf(whn[4*c+2], hcv[c].z, n); n = fmaf(whn[4*c+3], hcv[c].w, n);
      }
      pr[b] = r; pz[b] = z; pnh[b] = n;
    }
  };
  auto reduce_write = [&]() {
#pragma unroll
    for (int b = 0; b < 8; ++b) {
      pr[b] = row_reduce16(pr[b]);  pz[b] = row_reduce16(pz[b]);
      pni[b] = row_reduce16(pni[b]); pnh[b] = row_reduce16(pnh[b]);
    }
    if (kap == 15) {
#pragma unroll
      for (int b = 0; b < 8; ++b) {
        gsum[b*132 + uu]      = pr[b];
        gsum[b*132 + 32 + uu] = pz[b];
        gsum[b*132 + 64 + uu] = pni[b];
        gsum[b*132 + 96 + uu] = pnh[b];
      }
    }
  };
  // tid<256 only: full gate math; returns hnew and publishes it for step t.
  auto pointwise_h = [&](int t) -> float {
    float rr = sigm(gsum[b_l*132 + up]      + bihL[up]      + bhhL[up]);
    float zz = sigm(gsum[b_l*132 + 32 + up] + bihL[32 + up] + bhhL[32 + up]);
    float nn = ftanh(fmaf(rr, gsum[b_l*132 + 96 + up] + bhhL[64 + up],
                              gsum[b_l*132 + 64 + up] + bihL[64 + up]));
    float hold = hL[b_l*320 + ((j >> 4) * 20) + (j & 15)];
    float hnew = fmaf(zz, hold - nn, nn);
    agent_store_f32(P.hbuf + (((t + 1) & 1) * 65536) + bg * 256 + j, hnew);
    return hnew;
  };

  //================= Phase 1: backward GRU (phi1) =================
  load_whh_regs(P.p1_Whh);
  load_wih64_regs(P.p1_Wih);
  load_bias(P.p1_bih, P.p1_bhh);
  if (tid < 256) agent_store_f32(P.hbuf + bg * 256 + j, 0.0f);
  __syncthreads();  // fxwL ready before featurize
  {
    int bb = tid >> 6, k = tid & 63;
    float xv = P.x[(size_t)(g * 8 + bb) * 512 + 511];
    inL[bb * 68 + k] = ftanh(fmaf(xv, fxwL[k], fxbL[k]));
  }
  gbar();
#pragma unroll 1
  for (int t = 0; t < 512; ++t) {
    load_h_issue(t);
#pragma unroll
    for (int b = 0; b < 8; ++b) {  // gi overlaps LLC latency
      float4 iv = *(const float4*)(inL + b * 68 + kap * 4);
      pr[b]  = fmaf(wir[0], iv.x, fmaf(wir[1], iv.y, fmaf(wir[2], iv.z, wir[3] * iv.w)));
      pz[b]  = fmaf(wiz[0], iv.x, fmaf(wiz[1], iv.y, fmaf(wiz[2], iv.z, wiz[3] * iv.w)));
      pni[b] = fmaf(win[0], iv.x, fmaf(win[1], iv.y, fmaf(win[2], iv.z, win[3] * iv.w)));
      pnh[b] = 0.0f;
    }
    stage_h();
    __syncthreads();
    gh_accum();
    reduce_write();
    __syncthreads();
    int t_in = 511 - t;
    if (tid < 256) {
      float hnew = pointwise_h(t);
      P.xh[((size_t)wgid * 512 + t_in) * 256 + b_l * 32 + up] = __float2bfloat16(hnew);
    }
    if (t < 511) {
      int bb = tid >> 6, k = tid & 63;
      float xv = P.x[(size_t)(g * 8 + bb) * 512 + (t_in - 1)];
      inL[bb * 68 + k] = ftanh(fmaf(xv, fxwL[k], fxbL[k]));
    }
    gbar();
  }

  //================= Phase 2: encoder GRU (phi2) + posterior + feat_z =================
  load_whh_regs(P.p2_Whh);
  load_wih32_regs(P.p2_Wih);
  load_bias(P.p2_bih, P.p2_bhh);
  for (int idx = tid; idx < 2048; idx += 512) {
    int o = idx >> 9, c = idx & 511;
    SB[o * 516 + c] = P.pn_locW[idx];
    SB[2064 + o * 516 + c] = P.pn_scaleW[idx];
  }
  if (tid < 256) agent_store_f32(P.hbuf + bg * 256 + j, 0.0f);
  for (int idx = tid; idx < 8 * 36; idx += 512) inL[idx] = 0.0f;  // zf0 = 0
  gbar();
#pragma unroll 1
  for (int t = 0; t < 512; ++t) {
    load_h_issue(t);
#pragma unroll
    for (int b = 0; b < 8; ++b) {
      float2 iv = *(const float2*)(inL + b * 36 + kap * 2);
      pr[b]  = fmaf(wir[0], iv.x, wir[1] * iv.y);
      pz[b]  = fmaf(wiz[0], iv.x, wiz[1] * iv.y);
      pni[b] = fmaf(win[0], iv.x, win[1] * iv.y);
      pnh[b] = 0.0f;
    }
    stage_h();
    __syncthreads();
    gh_accum();
    reduce_write();
    __syncthreads();
    if (tid < 256) {
      float hnew = pointwise_h(t);
      float xhv = __bfloat162float(P.xh[((size_t)wgid * 512 + t) * 256 + b_l * 32 + up]);
      float p[8];
#pragma unroll
      for (int o = 0; o < 4; ++o)
        p[o] = fmaf(hnew, SB[o * 516 + j], xhv * SB[o * 516 + 256 + j]);
#pragma unroll
      for (int o = 0; o < 4; ++o)
        p[4 + o] = fmaf(hnew, SB[2064 + o * 516 + j], xhv * SB[2064 + o * 516 + 256 + j]);
#pragma unroll
      for (int o = 0; o < 8; ++o) {
        float v = p[o];
        v += __shfl_down(v, 32); v += __shfl_down(v, 16); v += __shfl_down(v, 8);
        p[o] = v;
      }
      int lane = tid & 63, wv = tid >> 6;
      if (lane < 8) {
#pragma unroll
        for (int o = 0; o < 8; ++o) wred[wv * 64 + lane * 8 + o] = p[o];
      }
    }
    __syncthreads();
    float* zp = P.zpart + (t & 1) * 16384 + g * 512;
    if (tid < 64) {
      int bb = tid >> 3, o = tid & 7;
      float sum = wred[bb*8+o] + wred[64+bb*8+o] + wred[128+bb*8+o] + wred[192+bb*8+o];
      agent_store_f32(zp + s * 64 + bb * 8 + o, sum);
    }
    gbar();
    if (tid < 64) {
      int bb = tid >> 3, o = tid & 7;
      float sum = 0.f;
#pragma unroll
      for (int sp = 0; sp < 8; ++sp) sum += agent_load_f32(zp + sp * 64 + bb * 8 + o);
      zred[bb * 8 + o] = sum;
    }
    __syncthreads();
    if (tid < 32) {
      int bb = tid >> 2, zi = tid & 3;
      float loc = zred[bb * 8 + zi] + pnlb[zi];
      float sc = softplusf(zred[bb * 8 + 4 + zi] + pnsb[zi]);
      float e = P.eps[((size_t)t * 256 + g * 8 + bb) * 4 + zi];
      ztL[bb * 4 + zi] = fmaf(sc, e, loc);
    }
    __syncthreads();
    if (tid < 16) {
      int bb = tid >> 1, m = tid & 1;
      float a = fzb1L[m];
#pragma unroll
      for (int i = 0; i < 4; ++i) a = fmaf(ztL[bb * 4 + i], fzW1L[m * 4 + i], a);
      hmL[bb * 2 + m] = ftanh(a);
    }
    __syncthreads();
    if (tid < 256) {
      int bb = tid >> 5, o = tid & 31;
      float zf = ftanh(fmaf(hmL[bb * 2], fzW2L[o * 2],
                       fmaf(hmL[bb * 2 + 1], fzW2L[o * 2 + 1], fzb2L[o])));
      inL[bb * 36 + o] = zf;
      if (s == 0) agent_store_f32(P.zf_seq + ((size_t)t * 256 + g * 8 + bb) * 32 + o, zf);
    }
    __syncthreads();
  }

  //================= Phase 3: decoder GRU (th) + output projection =================
  load_whh_regs(P.th_Whh);
  load_wih32_regs(P.th_Wih);
  load_bias(P.th_bih, P.th_bhh);
  if (tid < 256) agent_store_f32(P.hbuf + bg * 256 + j, 0.0f);
  gbar();
  const float tnb = P.tn_locb[0];
#pragma unroll 1
  for (int t = 0; t < 512; ++t) {
    load_h_issue(t);
    unsigned long long zq[8];
#pragma unroll
    for (int b = 0; b < 8; ++b)
      zq[b] = agent_load_u64((const unsigned long long*)P.zf_seq +
                             ((size_t)t * 256 + g * 8 + b) * 16 + kap);
#pragma unroll
    for (int b = 0; b < 8; ++b) {
      union { unsigned long long q; float f[2]; } zc; zc.q = zq[b];
      pr[b]  = fmaf(wir[0], zc.f[0], wir[1] * zc.f[1]);
      pz[b]  = fmaf(wiz[0], zc.f[0], wiz[1] * zc.f[1]);
      pni[b] = fmaf(win[0], zc.f[0], win[1] * zc.f[1]);
      pnh[b] = 0.0f;
    }
    stage_h();
    __syncthreads();
    gh_accum();
    reduce_write();
    __syncthreads();
    if (tid < 256) {
      float hnew = pointwise_h(t);
      float pv = hnew * tnwL[up];
      pv += __shfl_down(pv, 32); pv += __shfl_down(pv, 16); pv += __shfl_down(pv, 8);
      int lane = tid & 63, wv = tid >> 6;
      if (lane < 8) oredL[wv * 8 + lane] = pv;
    }
    __syncthreads();
    if (tid < 8) {
      float v = oredL[tid] + oredL[8 + tid] + oredL[16 + tid] + oredL[24 + tid];
      if (s == 0) v += tnb;
      atomicAdd(P.out + (size_t)(g * 8 + tid) * 512 + t, v);
    }
    gbar();
  }
}

extern "C" void kernel_launch(void* const* d_in, const int* in_sizes, int n_in,
                              void* d_out, int out_size, void* d_ws, size_t ws_size,
                              hipStream_t stream) {
  (void)in_sizes; (void)n_in; (void)ws_size;
  RvaeParams P;
  P.x        = (const float*)d_in[0];
  P.eps      = (const float*)d_in[1];
  P.fx_W     = (const float*)d_in[2];  P.fx_b     = (const float*)d_in[3];
  P.fz_W1    = (const float*)d_in[4];  P.fz_b1    = (const float*)d_in[5];
  P.fz_W2    = (const float*)d_in[6];  P.fz_b2    = (const float*)d_in[7];
  P.p1_Wih   = (const float*)d_in[8];  P.p1_Whh   = (const float*)d_in[9];
  P.p1_bih   = (const float*)d_in[10]; P.p1_bhh   = (const float*)d_in[11];
  P.p2_Wih   = (const float*)d_in[12]; P.p2_Whh   = (const float*)d_in[13];
  P.p2_bih   = (const float*)d_in[14]; P.p2_bhh   = (const float*)d_in[15];
  P.pn_locW  = (const float*)d_in[16]; P.pn_locb  = (const float*)d_in[17];
  P.pn_scaleW= (const float*)d_in[18]; P.pn_scaleb= (const float*)d_in[19];
  P.th_Wih   = (const float*)d_in[20]; P.th_Whh   = (const float*)d_in[21];
  P.th_bih   = (const float*)d_in[22]; P.th_bhh   = (const float*)d_in[23];
  P.tn_locW  = (const float*)d_in[24]; P.tn_locb  = (const float*)d_in[25];
  P.out = (float*)d_out;
  char* ws = (char*)d_ws;
  P.ctr    = (unsigned*)ws;                                    // 2048 B used
  P.hbuf   = (float*)(ws + 4096);                              // 524288 B
  P.zpart  = (float*)(ws + 4096 + 524288);                     // 131072 B
  P.zf_seq = (float*)(ws + 4096 + 524288 + 131072);            // 16777216 B
  P.xh = (__hip_bfloat16*)(ws + 4096 + 524288 + 131072 + 16777216); // 67108864 B

  hipMemsetAsync(d_out, 0, (size_t)out_size * sizeof(float), stream);
  hipMemsetAsync(d_ws, 0, 4096, stream);
  void* args[] = { (void*)&P };
  hipError_t err = hipLaunchCooperativeKernel((void*)rvae_main, dim3(256), dim3(512), args, 0, stream);
  if (err != hipSuccess) {
    hipLaunchKernelGGL(rvae_main, dim3(256), dim3(512), 0, stream, P);
  }
}